// Round 4
// baseline (1427.589 us; speedup 1.0000x reference)
//
#include <hip/hip_runtime.h>
#include <math.h>

#define BB 128
#define QQ 200
#define CC 92
#define CMPAD (QQ * QQ + 64) // pad so c3 = crow[192+t] stays in-bounds for t<64

// ---------------------------------------------------------------------------
__device__ __forceinline__ int rdlane_i(int x, int l) { return __builtin_amdgcn_readlane(x, l); }
__device__ __forceinline__ float rdlane_f(float x, int l) {
    return __uint_as_float((unsigned)__builtin_amdgcn_readlane((int)__float_as_uint(x), l));
}

// wave64 float min-reduce via DPP (row_shr 1/2/4/8, row_bcast 15/31), result
// broadcast from lane 63 as an SGPR. Float domain (v_min_f32): jnp.argmin
// compares floats, so equality-ballot against this min reproduces its
// semantics exactly (incl. -0==+0). No NaNs in this data.
__device__ __forceinline__ float wave_fmin_bcast(float x) {
    float y;
#define DPPSTEP(ctrl) \
    y = __uint_as_float((unsigned)__builtin_amdgcn_update_dpp( \
            (int)__float_as_uint(x), (int)__float_as_uint(x), ctrl, 0xf, 0xf, false)); \
    x = fminf(x, y);
    DPPSTEP(0x111) DPPSTEP(0x112) DPPSTEP(0x114) DPPSTEP(0x118)
    DPPSTEP(0x142) DPPSTEP(0x143)
#undef DPPSTEP
    return rdlane_f(x, 63);
}

// ---------------------------------------------------------------------------
// Fused kernel: R13 = R12's Hungarian main loop (byte-for-byte, measured
// 1282us) with the lse/cost kernels FUSED into the prologue. Rationale:
// cost_kernel was instruction-bound (~80us: 5.12M threads each paying 64-bit
// div/mod + scalar loads), and hungarian re-read its 20.5MB output from HBM.
// Here each block (1 wave, 1 batch) computes its 200x200 cost tile directly
// into LDS using the SAME fp ops in the SAME order as the old kernels:
//   lse:  m = seq fmax over 92; s = seq sum expf(x-m); lse = m + logf(s)
//   cost: ce = lse_i - pc[cls_j]; sl1 = sum_k smoothl1(d_k); ce + sl1*mask
// => bit-identical cost matrix => identical Hungarian trajectory.
// Lane t owns columns/rows j = t+64k (k=0..3; k=3 valid only for t<8).
// ---------------------------------------------------------------------------
__global__ __launch_bounds__(64) void hungarian_fused(const float* __restrict__ pc,
                                                      const float* __restrict__ pb,
                                                      const int*   __restrict__ tc,
                                                      const float* __restrict__ tb,
                                                      float* __restrict__ out) {
    const int b = blockIdx.x;
    const int t = threadIdx.x;

    __shared__ __align__(16) float cm[CMPAD];
    __shared__ float lse_s[QQ];

    const float INF = 1e9f;
    const int nval = (t < 8) ? 4 : 3;   // slot k valid iff t+64k < 200

    // ---- per-lane column constants (owned columns j = t+64k)
    int   cls[4];
    float tbx[4][4];
#pragma unroll
    for (int k = 0; k < 4; ++k) {
        if (k < nval) {
            int jj = t + 64 * k;
            cls[k] = tc[b * QQ + jj];
            const float4 v4 = *reinterpret_cast<const float4*>(tb + ((size_t)(b * QQ + jj)) * 4);
            tbx[k][0] = v4.x; tbx[k][1] = v4.y; tbx[k][2] = v4.z; tbx[k][3] = v4.w;
        } else {
            cls[k] = 0;
            tbx[k][0] = tbx[k][1] = tbx[k][2] = tbx[k][3] = 0.f;
        }
    }

    // ---- lse for owned rows r = t+64k (same op order as old lse_kernel)
#pragma unroll
    for (int k = 0; k < 4; ++k) {
        if (k < nval) {
            int r = t + 64 * k;
            const float* row = pc + ((size_t)(b * QQ + r)) * CC;
            float m = -INFINITY;
            for (int c = 0; c < CC; ++c) m = fmaxf(m, row[c]);
            float s = 0.f;
            for (int c = 0; c < CC; ++c) s += expf(row[c] - m);
            lse_s[r] = m + logf(s);
        }
    }
    __syncthreads();

    // ---- cost rows into cm (same fp expression/order as old cost_kernel)
#pragma unroll 2
    for (int i = 0; i < QQ; ++i) {
        const float4 pb4 = *reinterpret_cast<const float4*>(pb + ((size_t)(b * QQ + i)) * 4);
        const float pbb[4] = {pb4.x, pb4.y, pb4.z, pb4.w};
        const float lsei = lse_s[i];
        const float* pcrow = pc + ((size_t)(b * QQ + i)) * CC;
#pragma unroll
        for (int k = 0; k < 4; ++k) {
            if (k < nval) {
                float ce = lsei - pcrow[cls[k]];
                float sl1 = 0.f;
#pragma unroll
                for (int d = 0; d < 4; ++d) {
                    float df = pbb[d] - tbx[k][d];
                    float ad = fabsf(df);
                    sl1 += (ad < 1.f) ? 0.5f * df * df : (ad - 0.5f);
                }
                float mask = (cls[k] != 0) ? 1.f : 0.f;
                cm[i * QQ + t + 64 * k] = ce + sl1 * mask;
            }
        }
    }
    __syncthreads();

    // =======================================================================
    // Hungarian main loop — byte-for-byte R12 (measured 1282us, trajectory
    // bit-for-bit vs reference).
    // =======================================================================
    float v[4]     = {0.f, 0.f, 0.f, 0.f};
    int   pslot[4] = {0, 0, 0, 0};      // p for owned columns (0 = free)
    unsigned pp    = 0u;                // packed u8 shadow of pslot
    float uslot[4] = {0.f, 0.f, 0.f, 0.f};  // u of row matched to owned column
    float minv[4];
    int   waysl[4];
    int   usedm;
    float usent;

    for (int i = 1; i <= QQ; ++i) {
        minv[0] = minv[1] = minv[2] = minv[3] = INF;
        waysl[0] = waysl[1] = waysl[2] = waysl[3] = 0;
        usedm = 0;
        usent = 0.f;                    // u[i] == 0 at phase start
        int j0 = 0;
        float u0 = 0.f;                 // u[i0] for current iteration
        const float* crow = cm + (i - 1) * QQ;
        float c0 = crow[t];
        float c1 = crow[64 + t];
        float c2 = crow[128 + t];
        float c3 = crow[192 + t];       // pad keeps this in-bounds

        for (;;) {
            // ---- mark j0 used (owner lane)
            if (j0 > 0) {
                int s = (j0 - 1) >> 6;
                if (((j0 - 1) & 63) == t) usedm |= 1 << s;
            }

            // ---- scan owned columns (gated on !used: way entries freeze)
            float kv0, kv1, kv2, kv3;
            {
                float cur;
                cur = c0 - u0 - v[0];
                if (!(usedm & 1) && cur < minv[0]) { minv[0] = cur; waysl[0] = j0; }
                kv0 = (usedm & 1) ? INF : minv[0];
                cur = c1 - u0 - v[1];
                if (!(usedm & 2) && cur < minv[1]) { minv[1] = cur; waysl[1] = j0; }
                kv1 = (usedm & 2) ? INF : minv[1];
                cur = c2 - u0 - v[2];
                if (!(usedm & 4) && cur < minv[2]) { minv[2] = cur; waysl[2] = j0; }
                kv2 = (usedm & 4) ? INF : minv[2];
                cur = c3 - u0 - v[3];
                if (!(usedm & 8) && t < 8 && cur < minv[3]) { minv[3] = cur; waysl[3] = j0; }
                kv3 = ((usedm & 8) || t >= 8) ? INF : minv[3];
            }

            float gmin = wave_fmin_bcast(fminf(fminf(kv0, kv1), fminf(kv2, kv3)));
            float delta = gmin;

            // ---- smallest j with kv==gmin: k-major, lowest lane
            unsigned long long m0 = __ballot(kv0 == gmin);
            unsigned long long m1 = __ballot(kv1 == gmin);
            unsigned long long m2 = __ballot(kv2 == gmin);
            unsigned long long m3 = __ballot(kv3 == gmin);
            int j1;
            if (m0)      j1 = 1   + (int)__builtin_ctzll(m0);
            else if (m1) j1 = 65  + (int)__builtin_ctzll(m1);
            else if (m2) j1 = 129 + (int)__builtin_ctzll(m2);
            else         j1 = 193 + (int)__builtin_ctzll(m3);

            // ---- matched row + its dual from j1's owner lane (j1 uniform)
            int kk = (j1 - 1) >> 6, ln = (j1 - 1) & 63;
            float us = (kk == 0) ? uslot[0] : (kk == 1) ? uslot[1]
                      : (kk == 2) ? uslot[2] : uslot[3];
            // fast path: packed shadow, no select chain ahead of the readlane
            int pi = (int)(((unsigned)rdlane_i((int)pp, ln) >> (kk * 8)) & 255u);

            // ---- issue next row's reads NOW (cm immutable: no hazard);
            //      ~120cyc latency overlaps updates + u0n readlane below
            int nr = (pi > 0 ? pi : 1) - 1;
            const float* nrow = cm + nr * QQ;
            float n0 = nrow[t];
            float n1 = nrow[64 + t];
            float n2 = nrow[128 + t];
            float n3 = nrow[192 + t];

            float u0n = rdlane_f(us, ln);

            // ---- updates (identical fp-op sequence to reference)
#pragma unroll
            for (int k = 0; k < 4; ++k) {
                if (usedm & (1 << k)) {
                    v[k] -= delta;
                    uslot[k] += delta;               // == u[p[j]] += delta
                } else if (k < nval) {
                    minv[k] -= delta;
                }
            }
            usent += delta;                          // == u[i] += delta (sentinel)

            if (pi == 0) { j0 = j1; break; }
            j0 = j1; u0 = u0n;
            c0 = n0; c1 = n1; c2 = n2; c3 = n3;
        }

        // ---- augment: flip matching along alternating path (uniform walk;
        //      way/p/u served from registers via readlane; entries frozen)
        {
            int jj = j0;
            while (jj != 0) {
                int jm = jj - 1, km = jm >> 6, lm = jm & 63;
                int ws = (km == 0) ? waysl[0] : (km == 1) ? waysl[1]
                        : (km == 2) ? waysl[2] : waysl[3];
                int jn = rdlane_i(ws, lm);
                int pnew; float unew;
                if (jn == 0) {
                    pnew = i;                        // p[0] = i (sentinel)
                    unew = usent;                    // u[i] accumulated this phase
                } else {
                    int jm2 = jn - 1, kn = jm2 >> 6, ln2 = jm2 & 63;
                    int   ps2 = (kn == 0) ? pslot[0] : (kn == 1) ? pslot[1]
                               : (kn == 2) ? pslot[2] : pslot[3];
                    float us2 = (kn == 0) ? uslot[0] : (kn == 1) ? uslot[1]
                               : (kn == 2) ? uslot[2] : uslot[3];
                    pnew = rdlane_i(ps2, ln2);
                    unew = rdlane_f(us2, ln2);
                }
                if (lm == t) {
                    pslot[km] = pnew;
                    uslot[km] = unew;
                    int sh = km * 8;
                    pp = (pp & ~(255u << sh)) | ((unsigned)pnew << sh);
                }
                jj = jn;
            }
        }
    }

    // pslot[k] = row matched to owned column jc; emit per-row matched cost
#pragma unroll
    for (int k = 0; k < 4; ++k) {
        if (k < nval) {
            int jc = 1 + t + 64 * k;
            int row = pslot[k] - 1;
            out[b * QQ + row] = cm[row * QQ + (jc - 1)];
        }
    }
}

// ---------------------------------------------------------------------------
extern "C" void kernel_launch(void* const* d_in, const int* in_sizes, int n_in,
                              void* d_out, int out_size, void* d_ws, size_t ws_size,
                              hipStream_t stream) {
    const float* pred_cat  = (const float*)d_in[0];
    const float* pred_bbox = (const float*)d_in[1];
    const int*   tar_cat   = (const int*)d_in[2];
    const float* tar_bbox  = (const float*)d_in[3];
    float* out = (float*)d_out;
    (void)d_ws; (void)ws_size;

    hungarian_fused<<<BB, 64, 0, stream>>>(pred_cat, pred_bbox, tar_cat, tar_bbox, out);
}

// Round 5
// 1380.991 us; speedup vs baseline: 1.0337x; 1.0337x over previous
//
#include <hip/hip_runtime.h>
#include <math.h>

#define BB 128
#define QQ 200
#define CC 92
#define CMPAD (QQ * QQ + 64) // pad so c3 = crow[192+t] stays in-bounds for t<64

// ---------------------------------------------------------------------------
__device__ __forceinline__ int rdlane_i(int x, int l) { return __builtin_amdgcn_readlane(x, l); }
__device__ __forceinline__ float rdlane_f(float x, int l) {
    return __uint_as_float((unsigned)__builtin_amdgcn_readlane((int)__float_as_uint(x), l));
}

// wave64 float min-reduce via DPP (row_shr 1/2/4/8, row_bcast 15/31), result
// broadcast from lane 63 as an SGPR. Float domain (v_min_f32): jnp.argmin
// compares floats, so equality-ballot against this min reproduces its
// semantics exactly (incl. -0==+0). No NaNs in this data.
__device__ __forceinline__ float wave_fmin_bcast(float x) {
    float y;
#define DPPSTEP(ctrl) \
    y = __uint_as_float((unsigned)__builtin_amdgcn_update_dpp( \
            (int)__float_as_uint(x), (int)__float_as_uint(x), ctrl, 0xf, 0xf, false)); \
    x = fminf(x, y);
    DPPSTEP(0x111) DPPSTEP(0x112) DPPSTEP(0x114) DPPSTEP(0x118)
    DPPSTEP(0x142) DPPSTEP(0x143)
#undef DPPSTEP
    return rdlane_f(x, 63);
}

// ---------------------------------------------------------------------------
// Fused kernel, R14 = R13 with the prologue parallelized across 4 waves.
// R13 post-mortem: fusion removed 20.5MB write + 20.5MB re-read (FETCH 10->5.3
// MB) but the 1-wave prologue was latency-bound (~95us vs ~30us expected).
// Fix: launch 256 threads; all 4 waves cooperatively compute lse (1 row per
// thread, same sequential op order) and the cost tile (rows i = w, w+4, ...;
// identical per-element fp expression => bit-identical cm). One barrier, then
// waves 1-3 exit and wave 0 runs the R12 main loop (measured 1282us,
// trajectory bit-for-bit vs reference). No barrier after the early return.
// Lane t owns columns j = t+64k (k=0..3; k=3 valid only for t<8).
// ---------------------------------------------------------------------------
__global__ __launch_bounds__(256) void hungarian_fused(const float* __restrict__ pc,
                                                       const float* __restrict__ pb,
                                                       const int*   __restrict__ tc,
                                                       const float* __restrict__ tb,
                                                       float* __restrict__ out) {
    const int b = blockIdx.x;
    const int tid = threadIdx.x;
    const int w = tid >> 6;         // wave id 0..3
    const int t = tid & 63;         // lane id

    __shared__ __align__(16) float cm[CMPAD];
    __shared__ float lse_s[QQ];

    const float INF = 1e9f;
    const int nval = (t < 8) ? 4 : 3;   // slot k valid iff t+64k < 200

    // ---- per-lane column constants (owned columns j = t+64k); same per wave
    int   cls[4];
    float tbx[4][4];
#pragma unroll
    for (int k = 0; k < 4; ++k) {
        if (k < nval) {
            int jj = t + 64 * k;
            cls[k] = tc[b * QQ + jj];
            const float4 v4 = *reinterpret_cast<const float4*>(tb + ((size_t)(b * QQ + jj)) * 4);
            tbx[k][0] = v4.x; tbx[k][1] = v4.y; tbx[k][2] = v4.z; tbx[k][3] = v4.w;
        } else {
            cls[k] = 0;
            tbx[k][0] = tbx[k][1] = tbx[k][2] = tbx[k][3] = 0.f;
        }
    }

    // ---- lse: one row per thread (200 <= 256), same op order as reference
    if (tid < QQ) {
        const float* row = pc + ((size_t)(b * QQ + tid)) * CC;
        float m = -INFINITY;
        for (int c = 0; c < CC; ++c) m = fmaxf(m, row[c]);
        float s = 0.f;
        for (int c = 0; c < CC; ++c) s += expf(row[c] - m);
        lse_s[tid] = m + logf(s);
    }
    __syncthreads();

    // ---- cost rows into cm: wave w fills rows i = w, w+4, ... (50 each);
    //      identical per-element fp expression/order as reference
    for (int i = w; i < QQ; i += 4) {
        const float4 pb4 = *reinterpret_cast<const float4*>(pb + ((size_t)(b * QQ + i)) * 4);
        const float pbb[4] = {pb4.x, pb4.y, pb4.z, pb4.w};
        const float lsei = lse_s[i];
        const float* pcrow = pc + ((size_t)(b * QQ + i)) * CC;
#pragma unroll
        for (int k = 0; k < 4; ++k) {
            if (k < nval) {
                float ce = lsei - pcrow[cls[k]];
                float sl1 = 0.f;
#pragma unroll
                for (int d = 0; d < 4; ++d) {
                    float df = pbb[d] - tbx[k][d];
                    float ad = fabsf(df);
                    sl1 += (ad < 1.f) ? 0.5f * df * df : (ad - 0.5f);
                }
                float mask = (cls[k] != 0) ? 1.f : 0.f;
                cm[i * QQ + t + 64 * k] = ce + sl1 * mask;
            }
        }
    }
    __syncthreads();

    // ---- waves 1-3 done (no barriers below, so early exit is legal)
    if (tid >= 64) return;

    // =======================================================================
    // Hungarian main loop — byte-for-byte R12 (measured 1282us, trajectory
    // bit-for-bit vs reference).
    // =======================================================================
    float v[4]     = {0.f, 0.f, 0.f, 0.f};
    int   pslot[4] = {0, 0, 0, 0};      // p for owned columns (0 = free)
    unsigned pp    = 0u;                // packed u8 shadow of pslot
    float uslot[4] = {0.f, 0.f, 0.f, 0.f};  // u of row matched to owned column
    float minv[4];
    int   waysl[4];
    int   usedm;
    float usent;

    for (int i = 1; i <= QQ; ++i) {
        minv[0] = minv[1] = minv[2] = minv[3] = INF;
        waysl[0] = waysl[1] = waysl[2] = waysl[3] = 0;
        usedm = 0;
        usent = 0.f;                    // u[i] == 0 at phase start
        int j0 = 0;
        float u0 = 0.f;                 // u[i0] for current iteration
        const float* crow = cm + (i - 1) * QQ;
        float c0 = crow[t];
        float c1 = crow[64 + t];
        float c2 = crow[128 + t];
        float c3 = crow[192 + t];       // pad keeps this in-bounds

        for (;;) {
            // ---- mark j0 used (owner lane)
            if (j0 > 0) {
                int s = (j0 - 1) >> 6;
                if (((j0 - 1) & 63) == t) usedm |= 1 << s;
            }

            // ---- scan owned columns (gated on !used: way entries freeze)
            float kv0, kv1, kv2, kv3;
            {
                float cur;
                cur = c0 - u0 - v[0];
                if (!(usedm & 1) && cur < minv[0]) { minv[0] = cur; waysl[0] = j0; }
                kv0 = (usedm & 1) ? INF : minv[0];
                cur = c1 - u0 - v[1];
                if (!(usedm & 2) && cur < minv[1]) { minv[1] = cur; waysl[1] = j0; }
                kv1 = (usedm & 2) ? INF : minv[1];
                cur = c2 - u0 - v[2];
                if (!(usedm & 4) && cur < minv[2]) { minv[2] = cur; waysl[2] = j0; }
                kv2 = (usedm & 4) ? INF : minv[2];
                cur = c3 - u0 - v[3];
                if (!(usedm & 8) && t < 8 && cur < minv[3]) { minv[3] = cur; waysl[3] = j0; }
                kv3 = ((usedm & 8) || t >= 8) ? INF : minv[3];
            }

            float gmin = wave_fmin_bcast(fminf(fminf(kv0, kv1), fminf(kv2, kv3)));
            float delta = gmin;

            // ---- smallest j with kv==gmin: k-major, lowest lane
            unsigned long long m0 = __ballot(kv0 == gmin);
            unsigned long long m1 = __ballot(kv1 == gmin);
            unsigned long long m2 = __ballot(kv2 == gmin);
            unsigned long long m3 = __ballot(kv3 == gmin);
            int j1;
            if (m0)      j1 = 1   + (int)__builtin_ctzll(m0);
            else if (m1) j1 = 65  + (int)__builtin_ctzll(m1);
            else if (m2) j1 = 129 + (int)__builtin_ctzll(m2);
            else         j1 = 193 + (int)__builtin_ctzll(m3);

            // ---- matched row + its dual from j1's owner lane (j1 uniform)
            int kk = (j1 - 1) >> 6, ln = (j1 - 1) & 63;
            float us = (kk == 0) ? uslot[0] : (kk == 1) ? uslot[1]
                      : (kk == 2) ? uslot[2] : uslot[3];
            // fast path: packed shadow, no select chain ahead of the readlane
            int pi = (int)(((unsigned)rdlane_i((int)pp, ln) >> (kk * 8)) & 255u);

            // ---- issue next row's reads NOW (cm immutable: no hazard);
            //      ~120cyc latency overlaps updates + u0n readlane below
            int nr = (pi > 0 ? pi : 1) - 1;
            const float* nrow = cm + nr * QQ;
            float n0 = nrow[t];
            float n1 = nrow[64 + t];
            float n2 = nrow[128 + t];
            float n3 = nrow[192 + t];

            float u0n = rdlane_f(us, ln);

            // ---- updates (identical fp-op sequence to reference)
#pragma unroll
            for (int k = 0; k < 4; ++k) {
                if (usedm & (1 << k)) {
                    v[k] -= delta;
                    uslot[k] += delta;               // == u[p[j]] += delta
                } else if (k < nval) {
                    minv[k] -= delta;
                }
            }
            usent += delta;                          // == u[i] += delta (sentinel)

            if (pi == 0) { j0 = j1; break; }
            j0 = j1; u0 = u0n;
            c0 = n0; c1 = n1; c2 = n2; c3 = n3;
        }

        // ---- augment: flip matching along alternating path (uniform walk;
        //      way/p/u served from registers via readlane; entries frozen)
        {
            int jj = j0;
            while (jj != 0) {
                int jm = jj - 1, km = jm >> 6, lm = jm & 63;
                int ws = (km == 0) ? waysl[0] : (km == 1) ? waysl[1]
                        : (km == 2) ? waysl[2] : waysl[3];
                int jn = rdlane_i(ws, lm);
                int pnew; float unew;
                if (jn == 0) {
                    pnew = i;                        // p[0] = i (sentinel)
                    unew = usent;                    // u[i] accumulated this phase
                } else {
                    int jm2 = jn - 1, kn = jm2 >> 6, ln2 = jm2 & 63;
                    int   ps2 = (kn == 0) ? pslot[0] : (kn == 1) ? pslot[1]
                               : (kn == 2) ? pslot[2] : pslot[3];
                    float us2 = (kn == 0) ? uslot[0] : (kn == 1) ? uslot[1]
                               : (kn == 2) ? uslot[2] : uslot[3];
                    pnew = rdlane_i(ps2, ln2);
                    unew = rdlane_f(us2, ln2);
                }
                if (lm == t) {
                    pslot[km] = pnew;
                    uslot[km] = unew;
                    int sh = km * 8;
                    pp = (pp & ~(255u << sh)) | ((unsigned)pnew << sh);
                }
                jj = jn;
            }
        }
    }

    // pslot[k] = row matched to owned column jc; emit per-row matched cost
#pragma unroll
    for (int k = 0; k < 4; ++k) {
        if (k < nval) {
            int jc = 1 + t + 64 * k;
            int row = pslot[k] - 1;
            out[b * QQ + row] = cm[row * QQ + (jc - 1)];
        }
    }
}

// ---------------------------------------------------------------------------
extern "C" void kernel_launch(void* const* d_in, const int* in_sizes, int n_in,
                              void* d_out, int out_size, void* d_ws, size_t ws_size,
                              hipStream_t stream) {
    const float* pred_cat  = (const float*)d_in[0];
    const float* pred_bbox = (const float*)d_in[1];
    const int*   tar_cat   = (const int*)d_in[2];
    const float* tar_bbox  = (const float*)d_in[3];
    float* out = (float*)d_out;
    (void)d_ws; (void)ws_size;

    hungarian_fused<<<BB, 256, 0, stream>>>(pred_cat, pred_bbox, tar_cat, tar_bbox, out);
}